// Round 4
// baseline (181.918 us; speedup 1.0000x reference)
//
#include <hip/hip_runtime.h>
#include <stdint.h>

// Problem constants: B=2, S=2048, D=1024, H=16, HD=64
typedef unsigned short u16;
typedef unsigned int u32;
typedef __attribute__((ext_vector_type(8))) short bf16x8;   // 8 bf16 = 4 VGPR
typedef __attribute__((ext_vector_type(4))) float f32x4;
typedef __attribute__((ext_vector_type(4))) u32 u32x4;

#define MFMA16(a, b, c) __builtin_amdgcn_mfma_f32_16x16x32_bf16((a), (b), (c), 0, 0, 0)

// 0.125 (1/sqrt(HD)) * log2(e): folded into Q so softmax runs in exp2 domain
#define QSCALE 0.18033688011112042f

__device__ __forceinline__ u16 f2bf(float f) {  // round-to-nearest-even f32->bf16
  u32 u = __float_as_uint(f);
  u += 0x7fffu + ((u >> 16) & 1u);
  return (u16)(u >> 16);
}

__device__ __forceinline__ u32 cvt_pk_bf16(float a, float b) {  // lo=bf16(a), hi=bf16(b)
  u32 r;
  asm("v_cvt_pk_bf16_f32 %0, %1, %2" : "=v"(r) : "v"(a), "v"(b));
  return r;
}

__device__ __forceinline__ void load_lds16(const void* g, void* l) {
  __builtin_amdgcn_global_load_lds((const __attribute__((address_space(1))) void*)g,
                                   (__attribute__((address_space(3))) void*)l, 16, 0, 0);
}

// XOR swizzle for [*][64]-elem (128B-row) tiles
__device__ __forceinline__ int swz8(int row, int cb) {
  return row * 128 + ((cb ^ (row & 7)) << 4);
}

// ----------------------------------------------- fused prep: cast x, transpose W, mask bits
__global__ __launch_bounds__(256) void prep_kernel(const float4* __restrict__ x,
                                                   const int* __restrict__ mask,
                                                   const float* __restrict__ W0,
                                                   const float* __restrict__ W1,
                                                   const float* __restrict__ W2,
                                                   const float* __restrict__ W3,
                                                   ushort4* __restrict__ xbf,
                                                   u16* __restrict__ wt,
                                                   u32* __restrict__ MB) {
  const int bid = blockIdx.x, tid = threadIdx.x;
  __shared__ float t[32][33];
  if (bid < 1024) {
    // cast x -> bf16 (1,048,576 float4)
    for (int i = bid * 256 + tid; i < 1048576; i += 262144) {
      float4 v = x[i];
      ushort4 o;
      o.x = f2bf(v.x); o.y = f2bf(v.y); o.z = f2bf(v.z); o.w = f2bf(v.w);
      xbf[i] = o;
    }
  } else if (bid < 5120) {
    // transpose-cast the four weight matrices
    int r = bid - 1024;
    const int z = r >> 10; r &= 1023;
    const int by = (r >> 5) << 5, bx = (r & 31) << 5;
    const float* W = (z == 0) ? W0 : (z == 1) ? W1 : (z == 2) ? W2 : W3;
    u16* o = wt + (size_t)z * 1048576;
    const int tx = tid & 31, ty = tid >> 5;   // (32, 8)
#pragma unroll
    for (int j = 0; j < 32; j += 8) t[ty + j][tx] = W[(size_t)(by + ty + j) * 1024 + bx + tx];
    __syncthreads();
#pragma unroll
    for (int j = 0; j < 32; j += 8) o[(size_t)(bx + ty + j) * 1024 + by + tx] = f2bf(t[tx][ty + j]);
  } else {
    // mask -> bitmask. MB[(b*2048+q)*64 + w] covers k = w*32..w*32+31
    const int gtid = (bid - 5120) * 256 + tid;
    const int wid = gtid >> 6, lane = gtid & 63;
    for (int c = wid; c < 131072; c += 4096) {
      size_t base = ((size_t)(c >> 5)) * 2048 + (size_t)(c & 31) * 64;
      int v = mask[base + lane];
      unsigned long long bal = __ballot(v != 0);
      if (lane == 0) {
        MB[(size_t)c * 2]     = (u32)bal;
        MB[(size_t)c * 2 + 1] = (u32)(bal >> 32);
      }
    }
  }
}

// ------------------------------------------------------------------ GEMM (m97 structure)
// 128x128 tile, BK=64, linear LDS, global_load_lds(16) staging, 2 barriers / 32 MFMA.
// MODE 0: fused QKV (Bt = [Wq^T;Wk^T;Wv^T], N=3072) -> Q(scaled)/K at (bh,s,hd), V^T at (bh,hd,s)
// MODE 1: output projection -> f32 row-major + bias
template <int MODE>
__global__ __launch_bounds__(256) void gemm_kernel(const u16* __restrict__ A,
                                                   const u16* __restrict__ Bt,
                                                   u16* __restrict__ Qo, u16* __restrict__ Ko,
                                                   u16* __restrict__ Vo, float* __restrict__ Fo,
                                                   const float* __restrict__ bias) {
  __shared__ u16 As[128 * 64];   // 16 KB
  __shared__ u16 Bs[128 * 64];
  const int tid = threadIdx.x, lane = tid & 63;
  const int l15 = lane & 15, g = lane >> 4;
  const int wave = tid >> 6, wr = wave >> 1, wc = wave & 1;
  const int m0 = blockIdx.x * 128, n0 = blockIdx.y * 128;
  // staging: pass p covers rows p*32 + (tid>>3), 16B-chunk tid&7
  const char* Ag = (const char*)A + (size_t)(m0 + (tid >> 3)) * 2048 + (tid & 7) * 16;
  const char* Bg = (const char*)Bt + (size_t)(n0 + (tid >> 3)) * 2048 + (tid & 7) * 16;
  char* Asc = (char*)As;
  char* Bsc = (char*)Bs;
  char* ldA = Asc + wave * 1024;   // wave-uniform dest base (+ lane*16 by HW)
  char* ldB = Bsc + wave * 1024;

  f32x4 acc[4][4] = {};

  for (int kt = 0; kt < 16; ++kt) {
    const int kbyte = kt * 128;
    __syncthreads();                       // previous iteration's LDS reads done
#pragma unroll
    for (int p = 0; p < 4; ++p) {
      load_lds16(Ag + kbyte + p * 65536, ldA + p * 4096);
      load_lds16(Bg + kbyte + p * 65536, ldB + p * 4096);
    }
    __syncthreads();                       // drains vmcnt: staged data visible

    bf16x8 af[4][2], bfr[4][2];
#pragma unroll
    for (int i = 0; i < 4; ++i) {
      af[i][0] = *(const bf16x8*)(Asc + (wr * 64 + i * 16 + l15) * 128 + g * 16);
      af[i][1] = *(const bf16x8*)(Asc + (wr * 64 + i * 16 + l15) * 128 + 64 + g * 16);
    }
#pragma unroll
    for (int j = 0; j < 4; ++j) {
      bfr[j][0] = *(const bf16x8*)(Bsc + (wc * 64 + j * 16 + l15) * 128 + g * 16);
      bfr[j][1] = *(const bf16x8*)(Bsc + (wc * 64 + j * 16 + l15) * 128 + 64 + g * 16);
    }
#pragma unroll
    for (int kk = 0; kk < 2; ++kk)
#pragma unroll
      for (int i = 0; i < 4; ++i)
#pragma unroll
        for (int j = 0; j < 4; ++j)
          acc[i][j] = MFMA16(af[i][kk], bfr[j][kk], acc[i][j]);
  }

  // epilogue. C frag: col = lane&15, row = (lane>>4)*4 + r
  if (MODE == 1) {
#pragma unroll
    for (int i = 0; i < 4; ++i) {
      const int mrow = m0 + wr * 64 + i * 16 + g * 4;
#pragma unroll
      for (int j = 0; j < 4; ++j) {
        const int col = n0 + wc * 64 + j * 16 + l15;
        f32x4 v = acc[i][j];
#pragma unroll
        for (int r = 0; r < 4; ++r)
          Fo[(size_t)(mrow + r) * 1024 + col] = v[r] + bias[col];
      }
    }
  } else {
    const int which = n0 >> 10;                 // uniform per block
    const float scale = (which == 0) ? QSCALE : 1.0f;
    u16* outp = (which == 0) ? Qo : (which == 1) ? Ko : Vo;
#pragma unroll
    for (int i = 0; i < 4; ++i) {
      const int mrow = m0 + wr * 64 + i * 16 + g * 4;
      const int bb = mrow >> 11, s = mrow & 2047;
#pragma unroll
      for (int j = 0; j < 4; ++j) {
        const int col = (n0 + wc * 64 + j * 16 + l15) & 1023;
        const int h = col >> 6, hd = col & 63;
        f32x4 v = acc[i][j];
        if (which == 2) {
          u32 w0 = cvt_pk_bf16(v[0], v[1]);
          u32 w1 = cvt_pk_bf16(v[2], v[3]);
          *(uint2*)(outp + ((((size_t)(bb * 16 + h)) * 64 + hd) * 2048 + s)) = make_uint2(w0, w1);
        } else {
#pragma unroll
          for (int r = 0; r < 4; ++r)
            outp[(((size_t)(bb * 16 + h)) * 2048 + s + r) * 64 + hd] = f2bf(v[r] * scale);
        }
      }
    }
  }
}

// ---------------------------------------------------------------- flash attention
// grid (16 q-blocks of 128 rows, 32 bh). 512 thr = 8 waves. In-block split-K:
// waves 0-3 handle k in [0,1024), waves 4-7 k in [1024,2048), same 128 q-rows.
// Each wave owns 32 q-rows (2 q-frags). Swapped operands; P in registers via
// k-permuted V tile; mask applied as MFMA C-operand bias init; LDS merge epilogue.
__global__ __launch_bounds__(512, 4) void attn_kernel(const u16* __restrict__ Q,
                                                      const u16* __restrict__ K,
                                                      const u16* __restrict__ VT,
                                                      const u32* __restrict__ MB,
                                                      u16* __restrict__ CTX) {
  __shared__ u16 Kl[2][2][4096];   // [k-half][buf][64 k][64 hd] swizzled
  __shared__ u16 Vl[2][2][4096];   // [k-half][buf][64 hd][64 k] k-permuted + swizzled
  const int tid = threadIdx.x, lane = tid & 63, wave = tid >> 6;
  const int l15 = lane & 15, g = lane >> 4;
  const int hf = wave >> 2;        // which k-half this wave processes
  const int w4 = wave & 3;
  const int q0 = blockIdx.x * 128, bh = blockIdx.y;
  const int b = bh >> 4, h = bh & 15;
  const int qw0 = q0 + w4 * 32;

  // Q fragments (B operand of mfma(K,Q)): col=q, k-slice = hd 8g..8g+7 (+32 for kk=1)
  const char* Qb = (const char*)Q + ((size_t)bh * 2048 + qw0) * 128;
  const bf16x8 aq00 = *(const bf16x8*)(Qb + l15 * 128 + g * 16);
  const bf16x8 aq01 = *(const bf16x8*)(Qb + l15 * 128 + 64 + g * 16);
  const bf16x8 aq10 = *(const bf16x8*)(Qb + (16 + l15) * 128 + g * 16);
  const bf16x8 aq11 = *(const bf16x8*)(Qb + (16 + l15) * 128 + 64 + g * 16);

  const char* Kg = (const char*)K + ((size_t)bh * 2048 + hf * 1024) * 128;
  const char* Vg = (const char*)VT + (size_t)bh * 64 * 4096 + hf * 2048;
  const u32* mp0 = MB + ((size_t)b * 2048 + qw0 + l15) * 64 + hf * 32;
  const u32* mp1 = mp0 + 16 * 64;

  char* KlB = (char*)Kl + hf * 16384;
  char* VlB = (char*)Vl + hf * 16384;

  // staging coords (256 thr per half): rows sr, 32+sr; 16B chunk scb
  const int t2 = tid & 255;
  const int sr = t2 >> 3, scb = t2 & 7;
  const int vc0 = 2 * (scb & 1) + (scb & 4);  // V permuted chunk for k-quad 2*scb
  const int vh = (scb >> 1) & 1;              // 8B half

  // hoisted loop-invariant LDS byte offsets
  int koff[4][2], voff[2][4];
#pragma unroll
  for (int i = 0; i < 4; ++i) {
    koff[i][0] = swz8(i * 16 + l15, g);
    koff[i][1] = swz8(i * 16 + l15, 4 + g);
  }
#pragma unroll
  for (int ks = 0; ks < 2; ++ks)
#pragma unroll
    for (int j = 0; j < 4; ++j) voff[ks][j] = swz8(j * 16 + l15, ks * 4 + g);

  f32x4 oacc[4][2] = {};                       // [hd-frag j][q-frag f]
  float mrow[2] = {-1e30f, -1e30f}, lrow[2] = {0.f, 0.f};

  // prologue: stage this half's kb=0 into buf 0
  {
    bf16x8 k0 = *(const bf16x8*)(Kg + (size_t)sr * 128 + scb * 16);
    bf16x8 k1 = *(const bf16x8*)(Kg + (size_t)(32 + sr) * 128 + scb * 16);
    bf16x8 v0 = *(const bf16x8*)(Vg + (size_t)sr * 4096 + scb * 16);
    bf16x8 v1 = *(const bf16x8*)(Vg + (size_t)(32 + sr) * 4096 + scb * 16);
    *(bf16x8*)(KlB + swz8(sr, scb)) = k0;
    *(bf16x8*)(KlB + swz8(32 + sr, scb)) = k1;
    uint4 u0 = __builtin_bit_cast(uint4, v0);
    uint4 u1 = __builtin_bit_cast(uint4, v1);
    char* vb0 = VlB + sr * 128 + vh * 8;
    char* vb1 = VlB + (32 + sr) * 128 + vh * 8;
    *(uint2*)(vb0 + ((vc0 ^ (sr & 7)) << 4)) = make_uint2(u0.x, u0.y);
    *(uint2*)(vb0 + (((vc0 + 1) ^ (sr & 7)) << 4)) = make_uint2(u0.z, u0.w);
    *(uint2*)(vb1 + ((vc0 ^ ((32 + sr) & 7)) << 4)) = make_uint2(u1.x, u1.y);
    *(uint2*)(vb1 + (((vc0 + 1) ^ ((32 + sr) & 7)) << 4)) = make_uint2(u1.z, u1.w);
  }
  uint2 mcA = *(const uint2*)mp0;
  uint2 mcB = *(const uint2*)mp1;
  __syncthreads();

  int cur = 0;
  for (int kb = 0; kb < 16; ++kb) {
    const int kn = (kb < 15) ? kb + 1 : 15;
    // T14: issue next-tile loads now, ds_write them after compute
    bf16x8 k0 = *(const bf16x8*)(Kg + (size_t)(kn * 64 + sr) * 128 + scb * 16);
    bf16x8 k1 = *(const bf16x8*)(Kg + (size_t)(kn * 64 + 32 + sr) * 128 + scb * 16);
    bf16x8 v0 = *(const bf16x8*)(Vg + (size_t)sr * 4096 + kn * 128 + scb * 16);
    bf16x8 v1 = *(const bf16x8*)(Vg + (size_t)(32 + sr) * 4096 + kn * 128 + scb * 16);
    uint2 mn0 = *(const uint2*)(mp0 + (size_t)kn * 2);
    uint2 mn1 = *(const uint2*)(mp1 + (size_t)kn * 2);

    const char* Kc = KlB + cur * 8192;
    const char* Vc = VlB + cur * 8192;

    // ---- S^T = K Q^T with mask bias as C-init (masked -> -3e38, exp2 -> exact 0)
    f32x4 sa[2][4];
    __builtin_amdgcn_s_setprio(1);
#pragma unroll
    for (int i = 0; i < 4; ++i) {
      const u32 wiA = ((i & 2) ? mcA.y : mcA.x) >> ((i & 1) * 16 + g * 4);
      const u32 wiB = ((i & 2) ? mcB.y : mcB.x) >> ((i & 1) * 16 + g * 4);
      f32x4 bA, bB;
#pragma unroll
      for (int r = 0; r < 4; ++r) {
        bA[r] = (wiA & (1u << r)) ? 0.f : -3e38f;
        bB[r] = (wiB & (1u << r)) ? 0.f : -3e38f;
      }
      bf16x8 bk0 = *(const bf16x8*)(Kc + koff[i][0]);
      bf16x8 bk1 = *(const bf16x8*)(Kc + koff[i][1]);
      sa[0][i] = MFMA16(bk1, aq01, MFMA16(bk0, aq00, bA));
      sa[1][i] = MFMA16(bk1, aq11, MFMA16(bk0, aq10, bB));
    }
    __builtin_amdgcn_s_setprio(0);

    // ---- softmax per q-frag (in-lane + 2 shuffles)
    u32 Wp[2][8];
#pragma unroll
    for (int f = 0; f < 2; ++f) {
      float mx = fmaxf(
          fmaxf(fmaxf(fmaxf(sa[f][0][0], sa[f][0][1]), fmaxf(sa[f][0][2], sa[f][0][3])),
                fmaxf(fmaxf(sa[f][1][0], sa[f][1][1]), fmaxf(sa[f][1][2], sa[f][1][3]))),
          fmaxf(fmaxf(fmaxf(sa[f][2][0], sa[f][2][1]), fmaxf(sa[f][2][2], sa[f][2][3])),
                fmaxf(fmaxf(sa[f][3][0], sa[f][3][1]), fmaxf(sa[f][3][2], sa[f][3][3]))));
      mx = fmaxf(mx, __shfl_xor(mx, 16));
      mx = fmaxf(mx, __shfl_xor(mx, 32));
      // T13 defer-max: rescale only when max grew by > 8 (p bounded by 2^8)
      if (__any(mx > mrow[f] + 8.0f)) {
        const float nm = fmaxf(mrow[f], mx);
        const float sf = __builtin_amdgcn_exp2f(mrow[f] - nm);
        lrow[f] *= sf;
#pragma unroll
        for (int j = 0; j < 4; ++j) {
          oacc[j][f][0] *= sf; oacc[j][f][1] *= sf;
          oacc[j][f][2] *= sf; oacc[j][f][3] *= sf;
        }
        mrow[f] = nm;
      }
      float ps = 0.f;
#pragma unroll
      for (int i = 0; i < 4; ++i) {
        const float p0 = __builtin_amdgcn_exp2f(sa[f][i][0] - mrow[f]);
        const float p1 = __builtin_amdgcn_exp2f(sa[f][i][1] - mrow[f]);
        const float p2 = __builtin_amdgcn_exp2f(sa[f][i][2] - mrow[f]);
        const float p3 = __builtin_amdgcn_exp2f(sa[f][i][3] - mrow[f]);
        ps += (p0 + p1) + (p2 + p3);
        Wp[f][i * 2] = cvt_pk_bf16(p0, p1);
        Wp[f][i * 2 + 1] = cvt_pk_bf16(p2, p3);
      }
      ps += __shfl_xor(ps, 16);
      ps += __shfl_xor(ps, 32);
      lrow[f] += ps;
    }

    // ---- PV: ctx^T[hd][q] += V^T P^T. B-frag = lane's own words (V k-permutation).
    __builtin_amdgcn_s_setprio(1);
#pragma unroll
    for (int ks = 0; ks < 2; ++ks) {
      u32x4 t0 = {Wp[0][ks * 4], Wp[0][ks * 4 + 1], Wp[0][ks * 4 + 2], Wp[0][ks * 4 + 3]};
      u32x4 t1 = {Wp[1][ks * 4], Wp[1][ks * 4 + 1], Wp[1][ks * 4 + 2], Wp[1][ks * 4 + 3]};
      const bf16x8 ap0 = __builtin_bit_cast(bf16x8, t0);
      const bf16x8 ap1 = __builtin_bit_cast(bf16x8, t1);
#pragma unroll
      for (int j = 0; j < 4; ++j) {
        bf16x8 bv = *(const bf16x8*)(Vc + voff[ks][j]);
        oacc[j][0] = MFMA16(bv, ap0, oacc[j][0]);
        oacc[j][1] = MFMA16(bv, ap1, oacc[j][1]);
      }
    }
    __builtin_amdgcn_s_setprio(0);

    // ---- write next tile into other buffer, single barrier
    {
      char* Kd = KlB + (cur ^ 1) * 8192;
      char* Vd = VlB + (cur ^ 1) * 8192;
      *(bf16x8*)(Kd + swz8(sr, scb)) = k0;
      *(bf16x8*)(Kd + swz8(32 + sr, scb)) = k1;
      uint4 u0 = __builtin_bit_cast(uint4, v0);
      uint4 u1 = __builtin_bit_cast(uint4, v1);
      char* vb0 = Vd + sr * 128 + vh * 8;
      char* vb1 = Vd + (32 + sr) * 128 + vh * 8;
      *(uint2*)(vb0 + ((vc0 ^ (sr & 7)) << 4)) = make_uint2(u0.x, u0.y);
      *(uint2*)(vb0 + (((vc0 + 1) ^ (sr & 7)) << 4)) = make_uint2(u0.z, u0.w);
      *(uint2*)(vb1 + ((vc0 ^ ((32 + sr) & 7)) << 4)) = make_uint2(u1.x, u1.y);
      *(uint2*)(vb1 + (((vc0 + 1) ^ ((32 + sr) & 7)) << 4)) = make_uint2(u1.z, u1.w);
    }
    __syncthreads();
    cur ^= 1;
    mcA = mn0;
    mcB = mn1;
  }

  // ---- epilogue: merge the two k-halves through LDS, normalize, store CTX
  float* S = (float*)Kl;    // 4 waves x 64 lanes x 32 floats = 32 KB (all of Kl)
  float* Ms = (float*)Vl;   // 4 waves x 64 lanes x 4 floats
  if (hf == 1) {
    float* sp = S + ((size_t)(w4 * 64 + lane)) * 32;
#pragma unroll
    for (int f = 0; f < 2; ++f)
#pragma unroll
      for (int j = 0; j < 4; ++j) *(f32x4*)(sp + (f * 4 + j) * 4) = oacc[j][f];
    float* mpp = Ms + ((size_t)(w4 * 64 + lane)) * 4;
    mpp[0] = mrow[0]; mpp[1] = lrow[0]; mpp[2] = mrow[1]; mpp[3] = lrow[1];
  }
  __syncthreads();
  if (hf == 0) {
    const float* sp = S + ((size_t)(w4 * 64 + lane)) * 32;
    const float* mpp = Ms + ((size_t)(w4 * 64 + lane)) * 4;
#pragma unroll
    for (int f = 0; f < 2; ++f) {
      const float mo = mpp[f * 2], lo = mpp[f * 2 + 1];
      const float m = fmaxf(mrow[f], mo);
      const float c0 = __builtin_amdgcn_exp2f(mrow[f] - m);
      const float c1 = __builtin_amdgcn_exp2f(mo - m);
      const float denom = fmaxf(lrow[f] * c0 + lo * c1, 1e-30f);
      const float a0 = c0 / denom, a1 = c1 / denom;
      u16* Cb = CTX + ((size_t)(b * 2048 + qw0 + f * 16 + l15)) * 1024 + h * 64 + g * 4;
#pragma unroll
      for (int j = 0; j < 4; ++j) {
        f32x4 po = *(const f32x4*)(sp + (f * 4 + j) * 4);
        const float o0 = oacc[j][f][0] * a0 + po[0] * a1;
        const float o1 = oacc[j][f][1] * a0 + po[1] * a1;
        const float o2 = oacc[j][f][2] * a0 + po[2] * a1;
        const float o3 = oacc[j][f][3] * a0 + po[3] * a1;
        *(uint2*)(Cb + j * 16) = make_uint2(cvt_pk_bf16(o0, o1), cvt_pk_bf16(o2, o3));
      }
    }
  }
}

// ------------------------------------------------------------------------- launch
extern "C" void kernel_launch(void* const* d_in, const int* in_sizes, int n_in,
                              void* d_out, int out_size, void* d_ws, size_t ws_size,
                              hipStream_t stream) {
  const float* x   = (const float*)d_in[0];
  const int* amask = (const int*)d_in[1];
  const float* Wq  = (const float*)d_in[2];
  const float* Wk  = (const float*)d_in[3];
  const float* Wv  = (const float*)d_in[4];
  const float* Wo  = (const float*)d_in[5];
  const float* bo  = (const float*)d_in[6];

  // workspace layout (~51.4 MB)
  char* ws = (char*)d_ws;
  u16* xbf  = (u16*)(ws);                       // 8,388,608 B
  u16* wt   = (u16*)(ws + 8388608);             // 4 x 2,097,152 B (Wq^T,Wk^T,Wv^T,Wo^T bf16)
  u16* Qb   = (u16*)(ws + 16777216);            // (b,h,s,hd) bf16 (pre-scaled by QSCALE)
  u16* Kb   = (u16*)(ws + 25165824);            // (b,h,s,hd) bf16
  u16* VT   = (u16*)(ws + 33554432);            // (b,h,hd,s) bf16
  u16* CTX  = (u16*)(ws + 41943040);            // (b*s, h*hd) bf16
  u32* MB   = (u32*)(ws + 50331648);            // 1,048,576 B bitmask

  prep_kernel<<<6144, 256, 0, stream>>>((const float4*)x, amask, Wq, Wk, Wv, Wo,
                                        (ushort4*)xbf, wt, MB);

  gemm_kernel<0><<<dim3(32, 24), 256, 0, stream>>>(xbf, wt, Qb, Kb, VT, nullptr, nullptr);

  attn_kernel<<<dim3(16, 32), 512, 0, stream>>>(Qb, Kb, VT, MB, CTX);

  gemm_kernel<1><<<dim3(32, 8), 256, 0, stream>>>(CTX, wt + 3145728, nullptr, nullptr, nullptr,
                                                  (float*)d_out, bo);
}

// Round 5
// 159.954 us; speedup vs baseline: 1.1373x; 1.1373x over previous
//
#include <hip/hip_runtime.h>
#include <stdint.h>

// Problem constants: B=2, S=2048, D=1024, H=16, HD=64
typedef unsigned short u16;
typedef unsigned int u32;
typedef __attribute__((ext_vector_type(8))) short bf16x8;   // 8 bf16 = 4 VGPR
typedef __attribute__((ext_vector_type(4))) float f32x4;
typedef __attribute__((ext_vector_type(4))) u32 u32x4;

#define MFMA16(a, b, c) __builtin_amdgcn_mfma_f32_16x16x32_bf16((a), (b), (c), 0, 0, 0)

// 0.125 (1/sqrt(HD)) * log2(e): folded into Q so softmax runs in exp2 domain
#define QSCALE 0.18033688011112042f

__device__ __forceinline__ u16 f2bf(float f) {  // round-to-nearest-even f32->bf16
  u32 u = __float_as_uint(f);
  u += 0x7fffu + ((u >> 16) & 1u);
  return (u16)(u >> 16);
}

__device__ __forceinline__ u32 cvt_pk_bf16(float a, float b) {  // lo=bf16(a), hi=bf16(b)
  u32 r;
  asm("v_cvt_pk_bf16_f32 %0, %1, %2" : "=v"(r) : "v"(a), "v"(b));
  return r;
}

__device__ __forceinline__ void load_lds16(const void* g, void* l) {
  __builtin_amdgcn_global_load_lds((const __attribute__((address_space(1))) void*)g,
                                   (__attribute__((address_space(3))) void*)l, 16, 0, 0);
}

// XOR swizzle for [*][64]-elem (128B-row) tiles
__device__ __forceinline__ int swz8(int row, int cb) {
  return row * 128 + ((cb ^ (row & 7)) << 4);
}

// ----------------------------------------------- fused prep: cast x, transpose W, mask bits
__global__ __launch_bounds__(256) void prep_kernel(const float4* __restrict__ x,
                                                   const int* __restrict__ mask,
                                                   const float* __restrict__ W0,
                                                   const float* __restrict__ W1,
                                                   const float* __restrict__ W2,
                                                   const float* __restrict__ W3,
                                                   ushort4* __restrict__ xbf,
                                                   u16* __restrict__ wt,
                                                   u32* __restrict__ MB) {
  const int bid = blockIdx.x, tid = threadIdx.x;
  __shared__ float t[32][33];
  if (bid < 1024) {
    // cast x -> bf16 (1,048,576 float4)
    for (int i = bid * 256 + tid; i < 1048576; i += 262144) {
      float4 v = x[i];
      ushort4 o;
      o.x = f2bf(v.x); o.y = f2bf(v.y); o.z = f2bf(v.z); o.w = f2bf(v.w);
      xbf[i] = o;
    }
  } else if (bid < 5120) {
    // transpose-cast the four weight matrices
    int r = bid - 1024;
    const int z = r >> 10; r &= 1023;
    const int by = (r >> 5) << 5, bx = (r & 31) << 5;
    const float* W = (z == 0) ? W0 : (z == 1) ? W1 : (z == 2) ? W2 : W3;
    u16* o = wt + (size_t)z * 1048576;
    const int tx = tid & 31, ty = tid >> 5;   // (32, 8)
#pragma unroll
    for (int j = 0; j < 32; j += 8) t[ty + j][tx] = W[(size_t)(by + ty + j) * 1024 + bx + tx];
    __syncthreads();
#pragma unroll
    for (int j = 0; j < 32; j += 8) o[(size_t)(bx + ty + j) * 1024 + by + tx] = f2bf(t[tx][ty + j]);
  } else {
    // mask -> bitmask. MB[(b*2048+q)*64 + w] covers k = w*32..w*32+31
    const int gtid = (bid - 5120) * 256 + tid;
    const int wid = gtid >> 6, lane = gtid & 63;
    for (int c = wid; c < 131072; c += 4096) {
      size_t base = ((size_t)(c >> 5)) * 2048 + (size_t)(c & 31) * 64;
      int v = mask[base + lane];
      unsigned long long bal = __ballot(v != 0);
      if (lane == 0) {
        MB[(size_t)c * 2]     = (u32)bal;
        MB[(size_t)c * 2 + 1] = (u32)(bal >> 32);
      }
    }
  }
}

// ------------------------------------------------------------------ GEMM (m97 structure)
// 128x128 tile, BK=64, linear LDS, global_load_lds(16) staging, 2 barriers / 32 MFMA.
// MODE 0: fused QKV (Bt = [Wq^T;Wk^T;Wv^T], N=3072) -> Q(scaled)/K at (bh,s,hd), V^T at (bh,hd,s)
// MODE 1: output projection -> f32 row-major + bias
template <int MODE>
__global__ __launch_bounds__(256) void gemm_kernel(const u16* __restrict__ A,
                                                   const u16* __restrict__ Bt,
                                                   u16* __restrict__ Qo, u16* __restrict__ Ko,
                                                   u16* __restrict__ Vo, float* __restrict__ Fo,
                                                   const float* __restrict__ bias) {
  __shared__ u16 As[128 * 64];   // 16 KB
  __shared__ u16 Bs[128 * 64];
  const int tid = threadIdx.x, lane = tid & 63;
  const int l15 = lane & 15, g = lane >> 4;
  const int wave = tid >> 6, wr = wave >> 1, wc = wave & 1;
  const int m0 = blockIdx.x * 128, n0 = blockIdx.y * 128;
  // staging: pass p covers rows p*32 + (tid>>3), 16B-chunk tid&7
  const char* Ag = (const char*)A + (size_t)(m0 + (tid >> 3)) * 2048 + (tid & 7) * 16;
  const char* Bg = (const char*)Bt + (size_t)(n0 + (tid >> 3)) * 2048 + (tid & 7) * 16;
  char* Asc = (char*)As;
  char* Bsc = (char*)Bs;
  char* ldA = Asc + wave * 1024;   // wave-uniform dest base (+ lane*16 by HW)
  char* ldB = Bsc + wave * 1024;

  f32x4 acc[4][4] = {};

  for (int kt = 0; kt < 16; ++kt) {
    const int kbyte = kt * 128;
    __syncthreads();                       // previous iteration's LDS reads done
#pragma unroll
    for (int p = 0; p < 4; ++p) {
      load_lds16(Ag + kbyte + p * 65536, ldA + p * 4096);
      load_lds16(Bg + kbyte + p * 65536, ldB + p * 4096);
    }
    __syncthreads();                       // drains vmcnt: staged data visible

    bf16x8 af[4][2], bfr[4][2];
#pragma unroll
    for (int i = 0; i < 4; ++i) {
      af[i][0] = *(const bf16x8*)(Asc + (wr * 64 + i * 16 + l15) * 128 + g * 16);
      af[i][1] = *(const bf16x8*)(Asc + (wr * 64 + i * 16 + l15) * 128 + 64 + g * 16);
    }
#pragma unroll
    for (int j = 0; j < 4; ++j) {
      bfr[j][0] = *(const bf16x8*)(Bsc + (wc * 64 + j * 16 + l15) * 128 + g * 16);
      bfr[j][1] = *(const bf16x8*)(Bsc + (wc * 64 + j * 16 + l15) * 128 + 64 + g * 16);
    }
#pragma unroll
    for (int kk = 0; kk < 2; ++kk)
#pragma unroll
      for (int i = 0; i < 4; ++i)
#pragma unroll
        for (int j = 0; j < 4; ++j)
          acc[i][j] = MFMA16(af[i][kk], bfr[j][kk], acc[i][j]);
  }

  // epilogue. C frag: col = lane&15, row = (lane>>4)*4 + r
  if (MODE == 1) {
#pragma unroll
    for (int i = 0; i < 4; ++i) {
      const int mrow = m0 + wr * 64 + i * 16 + g * 4;
#pragma unroll
      for (int j = 0; j < 4; ++j) {
        const int col = n0 + wc * 64 + j * 16 + l15;
        f32x4 v = acc[i][j];
#pragma unroll
        for (int r = 0; r < 4; ++r)
          Fo[(size_t)(mrow + r) * 1024 + col] = v[r] + bias[col];
      }
    }
  } else {
    const int which = n0 >> 10;                 // uniform per block
    const float scale = (which == 0) ? QSCALE : 1.0f;
    u16* outp = (which == 0) ? Qo : (which == 1) ? Ko : Vo;
#pragma unroll
    for (int i = 0; i < 4; ++i) {
      const int mrow = m0 + wr * 64 + i * 16 + g * 4;
      const int bb = mrow >> 11, s = mrow & 2047;
#pragma unroll
      for (int j = 0; j < 4; ++j) {
        const int col = (n0 + wc * 64 + j * 16 + l15) & 1023;
        const int h = col >> 6, hd = col & 63;
        f32x4 v = acc[i][j];
        if (which == 2) {
          u32 w0 = cvt_pk_bf16(v[0], v[1]);
          u32 w1 = cvt_pk_bf16(v[2], v[3]);
          *(uint2*)(outp + ((((size_t)(bb * 16 + h)) * 64 + hd) * 2048 + s)) = make_uint2(w0, w1);
        } else {
#pragma unroll
          for (int r = 0; r < 4; ++r)
            outp[(((size_t)(bb * 16 + h)) * 2048 + s + r) * 64 + hd] = f2bf(v[r] * scale);
        }
      }
    }
  }
}

// ---------------------------------------------------------------- flash attention
// 512 blocks, 256 thr = 4 waves, each wave owns 32 q-rows (2 q-frags). KVBLK=128:
// one barrier / two 64-k subtiles. Swapped operands (lane owns q=l15 / 16+l15);
// P stays in registers via k-permuted V tile. Mask folded into MFMA C-operand init.
// XCD-pinned mapping: each XCD owns 4 bh (2MB K/V working set fits its 4MB L2).
__global__ __launch_bounds__(256, 2) void attn_kernel(const u16* __restrict__ Q,
                                                      const u16* __restrict__ K,
                                                      const u16* __restrict__ VT,
                                                      const u32* __restrict__ MB,
                                                      u16* __restrict__ CTX) {
  __shared__ u16 Kl[2][8192];     // [buf][128 k][64 hd], swizzled rows (16 KB/buf)
  __shared__ u16 Vl[2][8192];     // [buf][2 sub][64 hd][64 k] k-permuted + swizzled
  const int tid = threadIdx.x, lane = tid & 63, wave = tid >> 6;
  const int l15 = lane & 15, g = lane >> 4;
  // XCD-pinned block mapping (XCD = linear%8 heuristic; correctness-neutral)
  const int L = blockIdx.x + (blockIdx.y << 4);
  const int bh = ((L & 7) << 2) + ((L >> 3) & 3);
  const int q0 = (L >> 5) * 128;
  const int b = bh >> 4, h = bh & 15;
  const int qw0 = q0 + wave * 32;

  // Q fragments (B operand of mfma(K,Q)): col=q, k-slice = hd 8g..8g+7 (+32 for kk=1)
  const char* Qb = (const char*)Q + ((size_t)bh * 2048 + qw0) * 128;
  const bf16x8 aq00 = *(const bf16x8*)(Qb + l15 * 128 + g * 16);
  const bf16x8 aq01 = *(const bf16x8*)(Qb + l15 * 128 + 64 + g * 16);
  const bf16x8 aq10 = *(const bf16x8*)(Qb + (16 + l15) * 128 + g * 16);
  const bf16x8 aq11 = *(const bf16x8*)(Qb + (16 + l15) * 128 + 64 + g * 16);

  const char* Kg = (const char*)K + (size_t)bh * 2048 * 128;
  const char* Vg = (const char*)VT + (size_t)bh * 64 * 4096;
  const u32* mp0 = MB + ((size_t)b * 2048 + qw0 + l15) * 64;
  const u32* mp1 = mp0 + 16 * 64;

  // staging coords: rows sr + {0,32,64,96} (K) / per-sub rows sr, 32+sr (V); chunk scb
  const int sr = tid >> 3, scb = tid & 7;
  const int vc0 = 2 * (scb & 1) + (scb & 4);  // V permuted chunk for k-quad 2*scb
  const int vh = (scb >> 1) & 1;              // 8B half
  const int sw0 = (sr & 7) << 4, sw1 = ((32 + sr) & 7) << 4;

  // hoisted loop-invariant LDS byte offsets
  int koff[4][2], voff[2][4];
#pragma unroll
  for (int i = 0; i < 4; ++i) {
    koff[i][0] = swz8(i * 16 + l15, g);
    koff[i][1] = swz8(i * 16 + l15, 4 + g);
  }
#pragma unroll
  for (int ks = 0; ks < 2; ++ks)
#pragma unroll
    for (int j = 0; j < 4; ++j) voff[ks][j] = swz8(j * 16 + l15, ks * 4 + g);

  f32x4 oacc[4][2] = {};                       // [hd-frag j][q-frag f]
  float mrow[2] = {-1e30f, -1e30f}, lrow[2] = {0.f, 0.f};   // lrow: per-lane partial

#define STAGE_KV(dst_k, dst_v)                                                        \
  {                                                                                   \
    *(bf16x8*)((dst_k) + swz8(sr, scb)) = ka0;                                        \
    *(bf16x8*)((dst_k) + swz8(32 + sr, scb)) = ka1;                                   \
    *(bf16x8*)((dst_k) + swz8(64 + sr, scb)) = ka2;                                   \
    *(bf16x8*)((dst_k) + swz8(96 + sr, scb)) = ka3;                                   \
    uint4 u0 = __builtin_bit_cast(uint4, va0);                                        \
    uint4 u1 = __builtin_bit_cast(uint4, va1);                                        \
    uint4 u2 = __builtin_bit_cast(uint4, va2);                                        \
    uint4 u3 = __builtin_bit_cast(uint4, va3);                                        \
    char* b0 = (dst_v) + sr * 128 + vh * 8;                                           \
    char* b1 = (dst_v) + (32 + sr) * 128 + vh * 8;                                    \
    char* b2 = (dst_v) + 8192 + sr * 128 + vh * 8;                                    \
    char* b3 = (dst_v) + 8192 + (32 + sr) * 128 + vh * 8;                             \
    *(uint2*)(b0 + ((vc0 << 4) ^ sw0)) = make_uint2(u0.x, u0.y);                      \
    *(uint2*)(b0 + (((vc0 + 1) << 4) ^ sw0)) = make_uint2(u0.z, u0.w);                \
    *(uint2*)(b1 + ((vc0 << 4) ^ sw1)) = make_uint2(u1.x, u1.y);                      \
    *(uint2*)(b1 + (((vc0 + 1) << 4) ^ sw1)) = make_uint2(u1.z, u1.w);                \
    *(uint2*)(b2 + ((vc0 << 4) ^ sw0)) = make_uint2(u2.x, u2.y);                      \
    *(uint2*)(b2 + (((vc0 + 1) << 4) ^ sw0)) = make_uint2(u2.z, u2.w);                \
    *(uint2*)(b3 + ((vc0 << 4) ^ sw1)) = make_uint2(u3.x, u3.y);                      \
    *(uint2*)(b3 + (((vc0 + 1) << 4) ^ sw1)) = make_uint2(u3.z, u3.w);                \
  }

  // prologue: stage kb=0 into buf 0
  {
    bf16x8 ka0 = *(const bf16x8*)(Kg + (size_t)sr * 128 + scb * 16);
    bf16x8 ka1 = *(const bf16x8*)(Kg + (size_t)(32 + sr) * 128 + scb * 16);
    bf16x8 ka2 = *(const bf16x8*)(Kg + (size_t)(64 + sr) * 128 + scb * 16);
    bf16x8 ka3 = *(const bf16x8*)(Kg + (size_t)(96 + sr) * 128 + scb * 16);
    bf16x8 va0 = *(const bf16x8*)(Vg + (size_t)sr * 4096 + scb * 16);
    bf16x8 va1 = *(const bf16x8*)(Vg + (size_t)(32 + sr) * 4096 + scb * 16);
    bf16x8 va2 = *(const bf16x8*)(Vg + (size_t)sr * 4096 + 128 + scb * 16);
    bf16x8 va3 = *(const bf16x8*)(Vg + (size_t)(32 + sr) * 4096 + 128 + scb * 16);
    STAGE_KV((char*)Kl[0], (char*)Vl[0])
  }
  uint4 mcA = *(const uint4*)mp0;
  uint4 mcB = *(const uint4*)mp1;
  __syncthreads();

  int cur = 0;
  for (int kb = 0; kb < 16; ++kb) {
    const int kn = (kb < 15) ? kb + 1 : 15;
    // T14: issue next-tile loads now (a full double-subtile of compute away)
    const char* Kp = Kg + (size_t)kn * 16384;
    const char* Vp = Vg + (size_t)kn * 256;
    bf16x8 ka0 = *(const bf16x8*)(Kp + (size_t)sr * 128 + scb * 16);
    bf16x8 ka1 = *(const bf16x8*)(Kp + (size_t)(32 + sr) * 128 + scb * 16);
    bf16x8 ka2 = *(const bf16x8*)(Kp + (size_t)(64 + sr) * 128 + scb * 16);
    bf16x8 ka3 = *(const bf16x8*)(Kp + (size_t)(96 + sr) * 128 + scb * 16);
    bf16x8 va0 = *(const bf16x8*)(Vp + (size_t)sr * 4096 + scb * 16);
    bf16x8 va1 = *(const bf16x8*)(Vp + (size_t)(32 + sr) * 4096 + scb * 16);
    bf16x8 va2 = *(const bf16x8*)(Vp + (size_t)sr * 4096 + 128 + scb * 16);
    bf16x8 va3 = *(const bf16x8*)(Vp + (size_t)(32 + sr) * 4096 + 128 + scb * 16);
    uint4 mnA = *(const uint4*)(mp0 + (size_t)kn * 4);
    uint4 mnB = *(const uint4*)(mp1 + (size_t)kn * 4);

#pragma unroll
    for (int s = 0; s < 2; ++s) {
      const char* Kc = (const char*)Kl[cur] + s * 8192;
      const char* Vc = (const char*)Vl[cur] + s * 8192;
      const u32 mA0 = s ? mcA.z : mcA.x, mA1 = s ? mcA.w : mcA.y;
      const u32 mB0 = s ? mcB.z : mcB.x, mB1 = s ? mcB.w : mcB.y;

      // ---- S^T = K Q^T with mask bias as C-init (masked -> -3e38, exp2 -> exact 0)
      f32x4 sa[2][4];
      __builtin_amdgcn_s_setprio(1);
#pragma unroll
      for (int i = 0; i < 4; ++i) {
        const u32 wiA = ((i & 2) ? mA1 : mA0) >> ((i & 1) * 16 + g * 4);
        const u32 wiB = ((i & 2) ? mB1 : mB0) >> ((i & 1) * 16 + g * 4);
        f32x4 bA, bB;
#pragma unroll
        for (int r = 0; r < 4; ++r) {
          bA[r] = (wiA & (1u << r)) ? 0.f : -3e38f;
          bB[r] = (wiB & (1u << r)) ? 0.f : -3e38f;
        }
        bf16x8 bk0 = *(const bf16x8*)(Kc + koff[i][0]);
        bf16x8 bk1 = *(const bf16x8*)(Kc + koff[i][1]);
        sa[0][i] = MFMA16(bk1, aq01, MFMA16(bk0, aq00, bA));
        sa[1][i] = MFMA16(bk1, aq11, MFMA16(bk0, aq10, bB));
      }
      __builtin_amdgcn_s_setprio(0);

      // ---- softmax per q-frag (in-lane; only the max needs 2 shuffles)
      u32 Wp[2][8];
#pragma unroll
      for (int f = 0; f < 2; ++f) {
        float mx = fmaxf(
            fmaxf(fmaxf(fmaxf(sa[f][0][0], sa[f][0][1]), fmaxf(sa[f][0][2], sa[f][0][3])),
                  fmaxf(fmaxf(sa[f][1][0], sa[f][1][1]), fmaxf(sa[f][1][2], sa[f][1][3]))),
            fmaxf(fmaxf(fmaxf(sa[f][2][0], sa[f][2][1]), fmaxf(sa[f][2][2], sa[f][2][3])),
                  fmaxf(fmaxf(sa[f][3][0], sa[f][3][1]), fmaxf(sa[f][3][2], sa[f][3][3]))));
        mx = fmaxf(mx, __shfl_xor(mx, 16));
        mx = fmaxf(mx, __shfl_xor(mx, 32));
        // T13 defer-max: rescale only when max grew by > 8 (p bounded by 2^8)
        if (__any(mx > mrow[f] + 8.0f)) {
          const float nm = fmaxf(mrow[f], mx);
          const float sf = __builtin_amdgcn_exp2f(mrow[f] - nm);
          lrow[f] *= sf;
#pragma unroll
          for (int j = 0; j < 4; ++j) {
            oacc[j][f][0] *= sf; oacc[j][f][1] *= sf;
            oacc[j][f][2] *= sf; oacc[j][f][3] *= sf;
          }
          mrow[f] = nm;
        }
        float ps = 0.f;
#pragma unroll
        for (int i = 0; i < 4; ++i) {
          const float p0 = __builtin_amdgcn_exp2f(sa[f][i][0] - mrow[f]);
          const float p1 = __builtin_amdgcn_exp2f(sa[f][i][1] - mrow[f]);
          const float p2 = __builtin_amdgcn_exp2f(sa[f][i][2] - mrow[f]);
          const float p3 = __builtin_amdgcn_exp2f(sa[f][i][3] - mrow[f]);
          ps += (p0 + p1) + (p2 + p3);
          Wp[f][i * 2] = cvt_pk_bf16(p0, p1);
          Wp[f][i * 2 + 1] = cvt_pk_bf16(p2, p3);
        }
        lrow[f] += ps;                         // per-lane partial; reduced in epilogue
      }

      // ---- PV: ctx^T[hd][q] += V^T P^T. B-frag = lane's own words (V k-permutation).
      __builtin_amdgcn_s_setprio(1);
#pragma unroll
      for (int ks = 0; ks < 2; ++ks) {
        u32x4 t0 = {Wp[0][ks * 4], Wp[0][ks * 4 + 1], Wp[0][ks * 4 + 2], Wp[0][ks * 4 + 3]};
        u32x4 t1 = {Wp[1][ks * 4], Wp[1][ks * 4 + 1], Wp[1][ks * 4 + 2], Wp[1][ks * 4 + 3]};
        const bf16x8 ap0 = __builtin_bit_cast(bf16x8, t0);
        const bf16x8 ap1 = __builtin_bit_cast(bf16x8, t1);
#pragma unroll
        for (int j = 0; j < 4; ++j) {
          bf16x8 bv = *(const bf16x8*)(Vc + voff[ks][j]);
          oacc[j][0] = MFMA16(bv, ap0, oacc[j][0]);
          oacc[j][1] = MFMA16(bv, ap1, oacc[j][1]);
        }
      }
      __builtin_amdgcn_s_setprio(0);
    }

    // ---- write next tile into other buffer, single barrier
    STAGE_KV((char*)Kl[cur ^ 1], (char*)Vl[cur ^ 1])
    __syncthreads();
    cur ^= 1;
    mcA = mnA;
    mcB = mnB;
  }
#undef STAGE_KV

  // ---- epilogue: reduce lrow partials, normalize, store ctx as (b*s, h*64+hd) bf16
#pragma unroll
  for (int f = 0; f < 2; ++f) {
    float lr = lrow[f];
    lr += __shfl_xor(lr, 16);
    lr += __shfl_xor(lr, 32);
    const float inv = 1.0f / fmaxf(lr, 1e-30f);
    u16* Cb = CTX + ((size_t)(b * 2048 + qw0 + f * 16 + l15)) * 1024 + h * 64 + g * 4;
#pragma unroll
    for (int j = 0; j < 4; ++j) {
      u32 w0 = cvt_pk_bf16(oacc[j][f][0] * inv, oacc[j][f][1] * inv);
      u32 w1 = cvt_pk_bf16(oacc[j][f][2] * inv, oacc[j][f][3] * inv);
      *(uint2*)(Cb + j * 16) = make_uint2(w0, w1);
    }
  }
}

// ------------------------------------------------------------------------- launch
extern "C" void kernel_launch(void* const* d_in, const int* in_sizes, int n_in,
                              void* d_out, int out_size, void* d_ws, size_t ws_size,
                              hipStream_t stream) {
  const float* x   = (const float*)d_in[0];
  const int* amask = (const int*)d_in[1];
  const float* Wq  = (const float*)d_in[2];
  const float* Wk  = (const float*)d_in[3];
  const float* Wv  = (const float*)d_in[4];
  const float* Wo  = (const float*)d_in[5];
  const float* bo  = (const float*)d_in[6];

  // workspace layout (~51.4 MB)
  char* ws = (char*)d_ws;
  u16* xbf  = (u16*)(ws);                       // 8,388,608 B
  u16* wt   = (u16*)(ws + 8388608);             // 4 x 2,097,152 B (Wq^T,Wk^T,Wv^T,Wo^T bf16)
  u16* Qb   = (u16*)(ws + 16777216);            // (b,h,s,hd) bf16 (pre-scaled by QSCALE)
  u16* Kb   = (u16*)(ws + 25165824);            // (b,h,s,hd) bf16
  u16* VT   = (u16*)(ws + 33554432);            // (b,h,hd,s) bf16
  u16* CTX  = (u16*)(ws + 41943040);            // (b*s, h*hd) bf16
  u32* MB   = (u32*)(ws + 50331648);            // 1,048,576 B bitmask

  prep_kernel<<<6144, 256, 0, stream>>>((const float4*)x, amask, Wq, Wk, Wv, Wo,
                                        (ushort4*)xbf, wt, MB);

  gemm_kernel<0><<<dim3(32, 24), 256, 0, stream>>>(xbf, wt, Qb, Kb, VT, nullptr, nullptr);

  attn_kernel<<<dim3(16, 32), 256, 0, stream>>>(Qb, Kb, VT, MB, CTX);

  gemm_kernel<1><<<dim3(32, 8), 256, 0, stream>>>(CTX, wt + 3145728, nullptr, nullptr, nullptr,
                                                  (float*)d_out, bo);
}